// Round 9
// baseline (267.241 us; speedup 1.0000x reference)
//
#include <hip/hip_runtime.h>
#include <math.h>

// Problem constants
#define BATCH 2
#define SEQ   2048
#define NH    16
#define HD    64
#define DM    1024
#define MROWS (BATCH * SEQ)                  // 4096
#define NEL   ((size_t)MROWS * DM)           // 4 M elements (activation buffer)
#define WEL   ((size_t)DM * DM)              // 1 M elements (weight buffer)
// softmax scale folded into Q at projection: 1/sqrt(64) * log2(e)
#define SM_SCALE_LOG2E 0.18033688011112042f

typedef __bf16 bf16x8  __attribute__((ext_vector_type(8)));
typedef float  f32x16  __attribute__((ext_vector_type(16)));

#define MFMA32(a, b, c) __builtin_amdgcn_mfma_f32_32x32x16_bf16((a), (b), (c), 0, 0, 0)
#define EXP2(x) __builtin_amdgcn_exp2f(x)
// s_waitcnt vmcnt(0) (expcnt/lgkmcnt unconstrained): gfx9 encoding
#define WAITVM0 __builtin_amdgcn_s_waitcnt(0x0F70)

// async global->LDS, 16B per lane; LDS dest = wave-uniform base + lane*16
#define GLDS16(g, s) __builtin_amdgcn_global_load_lds( \
    (const __attribute__((address_space(1))) void*)(g), \
    (__attribute__((address_space(3))) void*)(s), 16, 0, 0)

// ======================================================================
// fp32 -> bf16 converts
// ======================================================================
__global__ __launch_bounds__(256) void cvt_x(const float* __restrict__ src,
                                             __bf16* __restrict__ dst) {
    const size_t i = ((size_t)blockIdx.x * 256 + threadIdx.x) * 4;
    const float4 f = *(const float4*)&src[i];
    __bf16 b[4] = {(__bf16)f.x, (__bf16)f.y, (__bf16)f.z, (__bf16)f.w};
    *(ushort4*)&dst[i] = *(ushort4*)b;
}

__global__ __launch_bounds__(256) void cvt_w(const float* __restrict__ w0,
                                             const float* __restrict__ w1,
                                             const float* __restrict__ w2,
                                             const float* __restrict__ w3,
                                             __bf16* __restrict__ dst) {
    const int z = blockIdx.z;
    const float* src = (z == 0) ? w0 : (z == 1) ? w1 : (z == 2) ? w2 : w3;
    __bf16* d = dst + (size_t)z * WEL;
    const size_t i = ((size_t)blockIdx.x * 256 + threadIdx.x) * 4;
    const float4 f = *(const float4*)&src[i];
    __bf16 b[4] = {(__bf16)f.x, (__bf16)f.y, (__bf16)f.z, (__bf16)f.w};
    *(ushort4*)&d[i] = *(ushort4*)b;
}

// ======================================================================
// WAVE-PRIVATE barrier-free NT bf16 GEMM. Each wave owns a 64x64 tile
// and a private 8 KB LDS slice (dbuf of 64x16 A + 64x16 B). No
// __syncthreads anywhere: the wave self-paces on vmcnt (prev iter's
// prefetch aliases the current buffer, so the compiler's conservative
// wait == the wait we want). Per iter: 4 ds_read_b128 + 4 GLDS + 4
// MFMA32. LDS XOR-swizzled (chunk h ^ (row&1)) -> conflict-free b128.
// mode 1: z selects weight+output slab; bf16 store permuted to
//   (B,H,S,HD); z==0 (Q) pre-scaled; z==2 (V) dual-stored to Vt.
// mode 0: fp32 row-major M x DM store.
// ======================================================================
__global__ __launch_bounds__(256, 4) void gemm_wp(
    const __bf16* __restrict__ A, const __bf16* __restrict__ W0,
    void* __restrict__ C0, __bf16* __restrict__ Vt, int mode)
{
    __shared__ __bf16 sg[4][2][2][64 * 16];   // [wave][buf][A|B]  32 KB

    const int t = threadIdx.x;
    const int w = t >> 6, l = t & 63;
    const int h = l >> 5, c = l & 31;
    const int z = blockIdx.z;
    const int gw = blockIdx.x * 4 + w;        // global wave-tile id
    const int nt = gw & 15, mt = gw >> 4;
    const int m0 = mt * 64, n0 = nt * 64;

    const __bf16* Wp = W0 + (size_t)z * WEL;

    const int lrow = l >> 1;                   // 0..31: staging row in instr
    const int lkof = ((l & 1) ^ (lrow & 1)) * 8;  // XOR-swizzled chunk
    const __bf16* Ag = A  + (size_t)(m0 + lrow) * DM + lkof;
    const __bf16* Bg = Wp + (size_t)(n0 + lrow) * DM + lkof;

    f32x16 acc[2][2];
    #pragma unroll
    for (int i = 0; i < 2; i++)
        #pragma unroll
        for (int j = 0; j < 2; j++) acc[i][j] = (f32x16)0.0f;

    // prologue: k-slice 0 -> buf 0
    GLDS16(Ag,            &sg[w][0][0][0]);
    GLDS16(Ag + 32 * DM,  &sg[w][0][0][512]);
    GLDS16(Bg,            &sg[w][0][1][0]);
    GLDS16(Bg + 32 * DM,  &sg[w][0][1][512]);

    for (int it = 0; it < DM / 16; it++) {
        const int cur = it & 1, nxt = cur ^ 1;
        WAITVM0;   // current buffer's 4 loads complete (wave-local)

        bf16x8 af[2], bfr[2];
        #pragma unroll
        for (int mb = 0; mb < 2; mb++)
            af[mb] = *(const bf16x8*)&sg[w][cur][0][(mb * 32 + c) * 16
                          + (h ^ (c & 1)) * 8];
        #pragma unroll
        for (int nb = 0; nb < 2; nb++)
            bfr[nb] = *(const bf16x8*)&sg[w][cur][1][(nb * 32 + c) * 16
                          + (h ^ (c & 1)) * 8];

        if (it + 1 < DM / 16) {               // prefetch after the reads
            const int k0 = (it + 1) * 16;
            GLDS16(Ag + k0,           &sg[w][nxt][0][0]);
            GLDS16(Ag + k0 + 32 * DM, &sg[w][nxt][0][512]);
            GLDS16(Bg + k0,           &sg[w][nxt][1][0]);
            GLDS16(Bg + k0 + 32 * DM, &sg[w][nxt][1][512]);
        }

        #pragma unroll
        for (int mb = 0; mb < 2; mb++)
            #pragma unroll
            for (int nb = 0; nb < 2; nb++)
                acc[mb][nb] = MFMA32(af[mb], bfr[nb], acc[mb][nb]);
    }

    if (mode) {
        const float sc = (z == 0) ? SM_SCALE_LOG2E : 1.0f;
        __bf16* C = (__bf16*)C0 + (size_t)z * NEL;
        #pragma unroll
        for (int mb = 0; mb < 2; mb++)
            #pragma unroll
            for (int nb = 0; nb < 2; nb++)
                #pragma unroll
                for (int g = 0; g < 4; g++)
                    #pragma unroll
                    for (int rr = 0; rr < 4; rr++) {
                        const int row = m0 + mb * 32 + rr + 8 * g + 4 * h;
                        const int col = n0 + nb * 32 + c;
                        const int b = row >> 11, s = row & (SEQ - 1);
                        const int hh = col >> 6, d = col & (HD - 1);
                        const __bf16 val = (__bf16)(acc[mb][nb][4 * g + rr] * sc);
                        C[((size_t)(b * NH + hh) * SEQ + s) * HD + d] = val;
                        if (z == 2)   // V: also store transposed (B,H,HD,S)
                            Vt[((size_t)(b * NH + hh) * HD + d) * SEQ + s] = val;
                    }
    } else {
        float* C = (float*)C0;
        #pragma unroll
        for (int mb = 0; mb < 2; mb++)
            #pragma unroll
            for (int nb = 0; nb < 2; nb++)
                #pragma unroll
                for (int g = 0; g < 4; g++)
                    #pragma unroll
                    for (int rr = 0; rr < 4; rr++) {
                        const int row = m0 + mb * 32 + rr + 8 * g + 4 * h;
                        const int col = n0 + nb * 32 + c;
                        C[(size_t)row * DM + col] = acc[mb][nb][4 * g + rr];
                    }
    }
}

// ======================================================================
// Flash attention v7: 32x32x16 MFMA, transposed-score, fixed-shift
// softmax (linear!), 2-way KEY-SPLIT across wave pairs, P transformed
// C-layout -> B-layout IN REGISTERS (quad pack + shfl_xor(32) + select,
// no P LDS at all), fused subtract-projection.
// Block = 128 q, 4 waves: w = (keypar<<1)|qhalf... w&1 = q-half (64 q),
// w>>1 = key parity (processes tiles 2t+kp). LDS = K/V dbuf 64 KB,
// XOR-swizzled. Partial (o,l) merged by addition through LDS at end
// (legal because no-max softmax is linear until the final normalize).
// ======================================================================
__global__ __launch_bounds__(256, 2) void attn_mfma(
    const __bf16* __restrict__ Q, const __bf16* __restrict__ K,
    const __bf16* __restrict__ Vt, const __bf16* __restrict__ V,
    const float* __restrict__ xsa, __bf16* __restrict__ X2)
{
    union SmU {
        struct {                       // [buf][slot=keypar][half][64r x 32]
            __bf16 Kt[2][2][2][64 * 32];
            __bf16 Vv[2][2][2][64 * 32];
        } kv;                          // 64 KB
        struct {                       // merge overlay (after final barrier)
            float o[2][64][68];        // [qhalf][lane][64 f32 + pad]
            float l[2][64][2];
        } mg;
    };
    __shared__ SmU sm;

    const int t = threadIdx.x;
    const int w = t >> 6, l = t & 63;
    const int h = l >> 5, c = l & 31;
    const int qh = w & 1, kp = w >> 1;
    const int bh = blockIdx.y;
    const int q0 = blockIdx.x * 128;

    const __bf16* Qb  = Q  + (size_t)bh * SEQ * HD;
    const __bf16* Kb  = K  + (size_t)bh * SEQ * HD;
    const __bf16* Vtb = Vt + (size_t)bh * HD * SEQ;

    const int lrow = l >> 2;
    const int lkof = ((l & 3) ^ (lrow & 3)) * 8;   // XOR-swizzled source chunk

    // ---- Q fragments: global -> registers (loop-invariant) ----
    bf16x8 qf[2][4];   // [qb][ks]  B-operand: n=q=c, k=d=ks*16+h*8+j
    #pragma unroll
    for (int qb = 0; qb < 2; qb++)
        #pragma unroll
        for (int ks = 0; ks < 4; ks++)
            qf[qb][ks] = *(const bf16x8*)&Qb[(size_t)(q0 + qh * 64 + qb * 32 + c) * HD
                                             + ks * 16 + h * 8];

    // ---- prologue: this wave stages half qh of tile-slot kp, buf 0 ----
    #pragma unroll
    for (int rb = 0; rb < 4; rb++)
        GLDS16(Kb + (size_t)(kp * 64 + rb * 16 + lrow) * HD + qh * 32 + lkof,
               &sm.kv.Kt[0][kp][qh][rb * 512]);
    #pragma unroll
    for (int rb = 0; rb < 4; rb++)
        GLDS16(Vtb + (size_t)(rb * 16 + lrow) * SEQ + kp * 64 + qh * 32 + lkof,
               &sm.kv.Vv[0][kp][qh][rb * 512]);
    __syncthreads();

    float l_i[2] = {0.0f, 0.0f};
    f32x16 o[2][2];   // [db][qb]   O^T: m=d, n=q
    #pragma unroll
    for (int db = 0; db < 2; db++)
        #pragma unroll
        for (int qb = 0; qb < 2; qb++) o[db][qb] = (f32x16)0.0f;

    for (int kt = 0; kt < 16; kt++) {
        const int cur = kt & 1, nxt = cur ^ 1;

        // ---- S^T = K Q^T : 64k x 64q x 64d (16 MFMA32, 8 kf reads) ----
        f32x16 st[2][2];   // [qb][kb]
        #pragma unroll
        for (int qb = 0; qb < 2; qb++)
            #pragma unroll
            for (int kb = 0; kb < 2; kb++) st[qb][kb] = (f32x16)0.0f;
        #pragma unroll
        for (int ks = 0; ks < 4; ks++) {
            bf16x8 kf[2];
            #pragma unroll
            for (int kb = 0; kb < 2; kb++)
                kf[kb] = *(const bf16x8*)&sm.kv.Kt[cur][kp][ks >> 1]
                             [(kb * 32 + c) * 32 + ((((ks & 1) * 2 + h) ^ (c & 3)) * 8)];
            #pragma unroll
            for (int qb = 0; qb < 2; qb++)
                #pragma unroll
                for (int kb = 0; kb < 2; kb++)
                    st[qb][kb] = MFMA32(kf[kb], qf[qb][ks], st[qb][kb]);
        }

        // ---- V fragments (read BEFORE prefetch so ds_reads precede GLDS)
        bf16x8 vf[2][4];   // [db][ksk]  A-op: m=d=db*32+c, k=key=ksk*16+h*8+j
        #pragma unroll
        for (int db = 0; db < 2; db++)
            #pragma unroll
            for (int ksk = 0; ksk < 4; ksk++)
                vf[db][ksk] = *(const bf16x8*)&sm.kv.Vv[cur][kp][ksk >> 1]
                    [(db * 32 + c) * 32 + ((((ksk & 1) * 2 + h) ^ (c & 3)) * 8)];

        // ---- prefetch next tile of this parity (flies under softmax+PV)
        if (kt + 1 < 16) {
            const int kb0 = (2 * (kt + 1) + kp) * 64;
            #pragma unroll
            for (int rb = 0; rb < 4; rb++)
                GLDS16(Kb + (size_t)(kb0 + rb * 16 + lrow) * HD + qh * 32 + lkof,
                       &sm.kv.Kt[nxt][kp][qh][rb * 512]);
            #pragma unroll
            for (int rb = 0; rb < 4; rb++)
                GLDS16(Vtb + (size_t)(rb * 16 + lrow) * SEQ + kb0 + qh * 32 + lkof,
                       &sm.kv.Vv[nxt][kp][qh][rb * 512]);
        }

        // ---- softmax + in-register P transform + PV, per qb ----
        #pragma unroll
        for (int qb = 0; qb < 2; qb++) {
            float rs = 0.0f;
            #pragma unroll
            for (int kb = 0; kb < 2; kb++)
                #pragma unroll
                for (int r = 0; r < 16; r++) {
                    const float p = EXP2(st[qb][kb][r]);
                    st[qb][kb][r] = p;
                    rs += p;
                }
            rs += __shfl_xor(rs, 32);
            l_i[qb] += rs;

            // pack each reg-quad (4 consecutive keys) to 4 bf16 = uint2
            uint2 pq[2][4], rq[2][4];
            #pragma unroll
            for (int kb = 0; kb < 2; kb++)
                #pragma unroll
                for (int g = 0; g < 4; g++) {
                    union { __bf16 b[4]; uint2 u; } x;
                    x.b[0] = (__bf16)st[qb][kb][4 * g + 0];
                    x.b[1] = (__bf16)st[qb][kb][4 * g + 1];
                    x.b[2] = (__bf16)st[qb][kb][4 * g + 2];
                    x.b[3] = (__bf16)st[qb][kb][4 * g + 3];
                    pq[kb][g] = x.u;
                    rq[kb][g].x = (unsigned)__shfl_xor((int)x.u.x, 32);
                    rq[kb][g].y = (unsigned)__shfl_xor((int)x.u.y, 32);
                }

            // assemble B-operand P^T frags: keys ksk*16 + h*8 + j, q=c
            #pragma unroll
            for (int ksk = 0; ksk < 4; ksk++) {
                const int kb = ksk >> 1, s = ksk & 1;
                union { uint4 u; bf16x8 v; } pf;
                pf.u.x = h ? rq[kb][2 * s + 1].x : pq[kb][2 * s].x;
                pf.u.y = h ? rq[kb][2 * s + 1].y : pq[kb][2 * s].y;
                pf.u.z = h ? pq[kb][2 * s + 1].x : rq[kb][2 * s].x;
                pf.u.w = h ? pq[kb][2 * s + 1].y : rq[kb][2 * s].y;
                #pragma unroll
                for (int db = 0; db < 2; db++)
                    o[db][qb] = MFMA32(vf[db][ksk], pf.v, o[db][qb]);
            }
        }

        __syncthreads();   // pair-wise staging fence + prefetch drain
    }

    // ---- merge key-parity partials (pure addition: linear softmax) ----
    if (kp == 1) {
        #pragma unroll
        for (int db = 0; db < 2; db++)
            #pragma unroll
            for (int qb = 0; qb < 2; qb++)
                #pragma unroll
                for (int g = 0; g < 4; g++)
                    *(float4*)&sm.mg.o[qh][l][((db * 2 + qb) * 4 + g) * 4] =
                        make_float4(o[db][qb][4 * g + 0], o[db][qb][4 * g + 1],
                                    o[db][qb][4 * g + 2], o[db][qb][4 * g + 3]);
        sm.mg.l[qh][l][0] = l_i[0];
        sm.mg.l[qh][l][1] = l_i[1];
    }
    __syncthreads();
    if (kp == 0) {
        #pragma unroll
        for (int db = 0; db < 2; db++)
            #pragma unroll
            for (int qb = 0; qb < 2; qb++)
                #pragma unroll
                for (int g = 0; g < 4; g++) {
                    const float4 m = *(const float4*)
                        &sm.mg.o[qh][l][((db * 2 + qb) * 4 + g) * 4];
                    o[db][qb][4 * g + 0] += m.x;
                    o[db][qb][4 * g + 1] += m.y;
                    o[db][qb][4 * g + 2] += m.z;
                    o[db][qb][4 * g + 3] += m.w;
                }
        l_i[0] += sm.mg.l[qh][l][0];
        l_i[1] += sm.mg.l[qh][l][1];

        // ---- epilogue: normalize, fused subtract-projection, store X2 ----
        const float xs = xsa[0];
        const int b = bh >> 4, hh = bh & (NH - 1);
        const __bf16* Vb = V + (size_t)bh * SEQ * HD;
        #pragma unroll
        for (int qb = 0; qb < 2; qb++) {
            const int q = q0 + qh * 64 + qb * 32 + c;
            const float inv = 1.0f / l_i[qb];
            float vv[2][4][4];
            float dp = 0.0f, nn = 0.0f;
            #pragma unroll
            for (int db = 0; db < 2; db++)
                #pragma unroll
                for (int g = 0; g < 4; g++) {
                    __bf16 vb4[4];
                    *(uint2*)vb4 = *(const uint2*)
                        &Vb[(size_t)q * HD + db * 32 + 8 * g + 4 * h];
                    #pragma unroll
                    for (int rr = 0; rr < 4; rr++) {
                        const float vfv = (float)vb4[rr];
                        const float of = o[db][qb][4 * g + rr] * inv;
                        vv[db][g][rr] = vfv;
                        dp += of * vfv;
                        nn += vfv * vfv;
                    }
                }
            dp += __shfl_xor(dp, 32);
            nn += __shfl_xor(nn, 32);
            const float coef = xs * dp / (nn + 1e-8f);
            #pragma unroll
            for (int db = 0; db < 2; db++)
                #pragma unroll
                for (int g = 0; g < 4; g++) {
                    __bf16 ob[4];
                    #pragma unroll
                    for (int rr = 0; rr < 4; rr++)
                        ob[rr] = (__bf16)(o[db][qb][4 * g + rr] * inv
                                          - coef * vv[db][g][rr]);
                    *(uint2*)&X2[((size_t)b * SEQ + q) * DM + hh * HD
                                 + db * 32 + 8 * g + 4 * h] = *(uint2*)ob;
                }
        }
    }
}

// ======================================================================
extern "C" void kernel_launch(void* const* d_in, const int* in_sizes, int n_in,
                              void* d_out, int out_size, void* d_ws, size_t ws_size,
                              hipStream_t stream)
{
    (void)in_sizes; (void)n_in; (void)out_size; (void)ws_size;
    const float* x   = (const float*)d_in[0];
    const float* Wq  = (const float*)d_in[1];
    const float* Wk  = (const float*)d_in[2];
    const float* Wv  = (const float*)d_in[3];
    const float* Wo  = (const float*)d_in[4];
    const float* xsa = (const float*)d_in[5];
    float* out = (float*)d_out;

    // workspace layout (bf16 elements): 56 MB total
    __bf16* xb  = (__bf16*)d_ws;        // 4 M
    __bf16* Wb  = xb  + NEL;            // 4 x 1 M (Wq,Wk,Wv,Wo)
    __bf16* Qb  = Wb  + 4 * WEL;        // 4 M  (B,H,S,HD), pre-scaled
    __bf16* Kb  = Qb  + NEL;            // 4 M
    __bf16* Vb  = Kb  + NEL;            // 4 M
    __bf16* Vtb = Vb  + NEL;            // 4 M  (B,H,HD,S)
    __bf16* X2  = Vtb + NEL;            // 4 M  (B,S,DM)

    cvt_x<<<dim3(NEL / 1024), 256, 0, stream>>>(x, xb);
    cvt_w<<<dim3(WEL / 1024, 1, 4), 256, 0, stream>>>(Wq, Wk, Wv, Wo, Wb);

    // Q/K/V projections: 1024 wave-tiles per z, 4 waves/block, barrier-free
    gemm_wp<<<dim3(256, 1, 3), 256, 0, stream>>>(xb, Wb, Qb, Vtb, 1);

    // attention + fused subtract-projection -> X2
    attn_mfma<<<dim3(SEQ / 128, BATCH * NH), 256, 0, stream>>>(
        Qb, Kb, Vtb, Vb, xsa, X2);

    // output projection: 1024 wave-tiles, barrier-free, fp32 out
    gemm_wp<<<dim3(256, 1, 1), 256, 0, stream>>>(
        X2, Wb + 3 * WEL, out, nullptr, 0);
}